// Round 8
// baseline (291.963 us; speedup 1.0000x reference)
//
#include <hip/hip_runtime.h>

// OU Euler-Maruyama: x_{i+1} = a*x_i + b_i,  a = 1 - gamma*dt (per-chain const),
// b_i = gamma*mu*dt + sigma*sqrt(dt)*eps_i.
//
// FREE-RUNNING single-wave pipelines. 4 independent waves per 256-thr block,
// one chain per wave (512 blocks, 2048 waves, 8 waves/CU). NO __syncthreads,
// NO LDS, no inter-wave coupling: waves drift apart (desynchronizing the
// chip-wide load/compute phase lockstep that R1-R7 all shared and that left
// every design at ~100us / 2.45 TB/s with ~85% memory-wait at 31% HBM util).
//
// True 16-deep double-banked register ring: cA[16]/cB[16] float4 (128 VGPRs,
// verifiable in VGPR_Count). Per group of 16 tiles: batch-issue the next
// bank's 16 coalesced loads, then sched_barrier(0) (stops the scheduler
// sinking loads into the consume code - the R1/R6/R7 defeat), then consume
// the current bank: per tile a uniform-weight wave scan (1 shfl + 1 fma per
// step), serial xw carry in registers, full-line NT store.
//
// Tile = 256 floats (lane owns 4, coalesced). 80 tiles: 0..77 full, 78
// partial (32 floats, lanes 0-7), 79 void (loads/stores provably DCE'd).
// Banks zero-initialized so never-loaded slots can't inject NaN into
// discarded lanes.

#define T_STEPS 20000
#define M_PATHS 64
#define NWAVES  4
#define BLOCK   (NWAVES * 64)          // 256
#define TILE_F  256                    // floats per wave-tile
#define NTILES  80                     // 5 groups of 16 (78 full, 1 partial, 1 void)
#define DEPTH   16                     // ring bank depth (tiles)
#define DT      0.01f
#define SQRT_DT 0.1f

typedef float f32x4 __attribute__((ext_vector_type(4)));

__global__ __launch_bounds__(BLOCK, 2) void ou_scan_kernel(
    const float* __restrict__ theta,
    const float* __restrict__ noise,
    float* __restrict__ out)
{
    const int tid   = threadIdx.x;
    const int wave  = tid >> 6;
    const int lane  = tid & 63;
    const int chain = blockIdx.x * NWAVES + wave;   // 0 .. 2047
    const int n     = chain >> 6;                   // theta row

    const float gamma = theta[n * 4 + 0];
    const float mu    = theta[n * 4 + 1];
    const float sigma = theta[n * 4 + 2];
    float xw          = theta[n * 4 + 3];           // running state (x_0)

    const float a    = 1.0f - gamma * DT;
    const float gmdt = gamma * mu * DT;
    const float ssd  = sigma * SQRT_DT;

    const float a2   = a * a;
    const float a4   = a2 * a2;
    const float a8   = a4 * a4;
    const float a16  = a8 * a8;
    const float a32  = a16 * a16;
    const float a64  = a32 * a32;
    const float a128 = a64 * a64;
    const float a256 = a128 * a128;    // per-tile carry multiplier

    // per-lane position multiplier within a tile: a^(4*lane)
    float Aex = 1.f;
    if (lane & 1)  Aex *= a4;
    if (lane & 2)  Aex *= a8;
    if (lane & 4)  Aex *= a16;
    if (lane & 8)  Aex *= a32;
    if (lane & 16) Aex *= a64;
    if (lane & 32) Aex *= a128;

    const float* __restrict__ np_ = noise + (size_t)chain * T_STEPS;
    float* __restrict__       op_ = out   + (size_t)chain * T_STEPS;
    const int loff = lane << 2;

    // guarded coalesced tile load (tile is compile-time after unrolling;
    // tile 79's guard is provably false -> load DCE'd)
    auto ld = [&](const int tile) -> float4 {
        const int e = tile * TILE_F + loff;
        if (e + 4 <= T_STEPS) return *(const float4*)(np_ + e);
        return make_float4(0.f, 0.f, 0.f, 0.f);
    };

    // consume one tile: uniform-weight wave scan + NT store; advances xw
    auto do_tile = [&](const float4 cv, const int tile) {
        const int  e   = tile * TILE_F + loff;
        const bool act = (e + 4 <= T_STEPS);   // const-folded for tiles<78

        const float b0 = fmaf(ssd, cv.x, gmdt);
        const float b1 = fmaf(ssd, cv.y, gmdt);
        const float b2 = fmaf(ssd, cv.z, gmdt);
        const float b3 = fmaf(ssd, cv.w, gmdt);
        float p = b0;
        p = fmaf(p, a, b1);
        p = fmaf(p, a, b2);
        p = fmaf(p, a, b3);

        float B = act ? p : 0.f;
        {
            float t;
            t = __shfl_up(B, 1);  if (lane >= 1)  B = fmaf(a4,   t, B);
            t = __shfl_up(B, 2);  if (lane >= 2)  B = fmaf(a8,   t, B);
            t = __shfl_up(B, 4);  if (lane >= 4)  B = fmaf(a16,  t, B);
            t = __shfl_up(B, 8);  if (lane >= 8)  B = fmaf(a32,  t, B);
            t = __shfl_up(B, 16); if (lane >= 16) B = fmaf(a64,  t, B);
            t = __shfl_up(B, 32); if (lane >= 32) B = fmaf(a128, t, B);
        }

        float Bex = __shfl_up(B, 1);
        if (lane == 0) Bex = 0.f;
        float x = fmaf(Aex, xw, Bex);          // state entering this lane

        const float B63 = __shfl(B, 63);
        xw = fmaf(a256, xw, B63);              // serial carry (regs only)
        // (after tile 78 xw is polluted by the uniform-weight treatment of
        //  inactive steps, but tiles >78 store nothing)

        if (act) {
            f32x4 o;
            x = fmaf(a, x, b0); o.x = x;
            x = fmaf(a, x, b1); o.y = x;
            x = fmaf(a, x, b2); o.z = x;
            x = fmaf(a, x, b3); o.w = x;
            __builtin_nontemporal_store(o, (f32x4*)(op_ + e));
        }
    };

    float4 cA[DEPTH], cB[DEPTH];
    #pragma unroll
    for (int s = 0; s < DEPTH; ++s) {         // never-loaded slots must not
        cA[s] = make_float4(0.f, 0.f, 0.f, 0.f);   // inject NaN
        cB[s] = make_float4(0.f, 0.f, 0.f, 0.f);
    }

    // prologue: bank A <- tiles 0..15
    #pragma unroll
    for (int s = 0; s < DEPTH; ++s) cA[s] = ld(s);
    __builtin_amdgcn_sched_barrier(0);

    // 5 groups: issue next bank's loads, fence, consume current bank
    #pragma unroll
    for (int g = 0; g < 5; ++g) {
        if (g < 4) {
            if (g & 1) {
                #pragma unroll
                for (int s = 0; s < DEPTH; ++s) cA[s] = ld((g + 1) * DEPTH + s);
            } else {
                #pragma unroll
                for (int s = 0; s < DEPTH; ++s) cB[s] = ld((g + 1) * DEPTH + s);
            }
        }
        __builtin_amdgcn_sched_barrier(0);   // loads stay issued above consume
        if (g & 1) {
            #pragma unroll
            for (int s = 0; s < DEPTH; ++s) do_tile(cB[s], g * DEPTH + s);
        } else {
            #pragma unroll
            for (int s = 0; s < DEPTH; ++s) do_tile(cA[s], g * DEPTH + s);
        }
    }
}

extern "C" void kernel_launch(void* const* d_in, const int* in_sizes, int n_in,
                              void* d_out, int out_size, void* d_ws, size_t ws_size,
                              hipStream_t stream) {
    const float* theta = (const float*)d_in[0];
    const float* noise = (const float*)d_in[1];
    float* out = (float*)d_out;

    const int chains = in_sizes[1] / T_STEPS;   // 2048
    const int blocks = chains / NWAVES;         // 512
    ou_scan_kernel<<<blocks, BLOCK, 0, stream>>>(theta, noise, out);
}